// Round 6
// baseline (234.598 us; speedup 1.0000x reference)
//
#include <hip/hip_runtime.h>

#define N_NODES 65536
#define B_G     64
#define NPG     1024
#define KC      128
#define DIN     128
#define E_EDGES 1048576
#define EPG     16384
#define NSLICE  8
#define SLICE_E (EPG / NSLICE)    // 2048 edges per slice
#define CSTRIDE (EPG + NPG)       // per-graph CSR slots (even-padded offsets)
#define NSTR    136               // ldsN/ldsP row stride (shorts), 272 B, 16B-aligned

typedef __attribute__((ext_vector_type(8))) short short8;
typedef __attribute__((ext_vector_type(4))) float floatx4;

static __device__ __forceinline__ short f2bf(float x) {
    unsigned u = __float_as_uint(x);
    unsigned r = (u + 0x7FFF + ((u >> 16) & 1)) >> 16;
    return (short)r;
}
static __device__ __forceinline__ unsigned pack2(float a, float b) {
    return (unsigned)(unsigned short)f2bf(a) | ((unsigned)(unsigned short)f2bf(b) << 16);
}

// ================ setup_a: blocks 0..511 = per-(graph,slice) degree histogram;
//                  blocks 512.. = wt / feaT / h_bf conversions
__global__ __launch_bounds__(256) void setup_a(
    const float* __restrict__ Wself, const float* __restrict__ Wneigh,
    const float* __restrict__ fea, const float* __restrict__ h,
    const int* __restrict__ edst,
    short* __restrict__ wt, short* __restrict__ feaT, short* __restrict__ h_bf,
    int* __restrict__ slicecnt)
{
    int bid = blockIdx.x;
    int tid = threadIdx.x;
    if (bid < B_G * NSLICE) {
        __shared__ int cnt[NPG];
        int g = bid >> 3, s = bid & 7;
        int gbase = g << 10;
        for (int i = tid; i < NPG; i += 256) cnt[i] = 0;
        __syncthreads();
        const int* ed = edst + (size_t)g * EPG + s * SLICE_E;
#pragma unroll
        for (int it = 0; it < SLICE_E / 256; it++)
            atomicAdd(&cnt[ed[it * 256 + tid] - gbase], 1);
        __syncthreads();
        int* sc = slicecnt + ((size_t)bid << 10);
        for (int i = tid; i < NPG; i += 256) sc[i] = cnt[i];
    } else {
        long idx = (long)(bid - B_G * NSLICE) * 256 + tid;
        if (idx < 32768) {
            int n = (int)(idx >> 8), k = (int)(idx & 255);
            float v = (k < 128) ? Wself[k * 128 + n] : Wneigh[(k - 128) * 128 + n];
            wt[idx] = f2bf(v);
        } else if (idx < 32768 + 1048576) {
            long fi = idx - 32768;
            int g = (int)(fi >> 14), d = (int)((fi >> 7) & 127), k = (int)(fi & 127);
            feaT[fi] = f2bf(fea[((long)g * 128 + k) * 128 + d]);
        } else {
            long gi = idx - 32768 - 1048576;   // 8 floats per item
            const float4* hp = (const float4*)h + gi * 2;
            float4 a = hp[0], b4 = hp[1];
            uint4 w;
            w.x = pack2(a.x, a.y);
            w.y = pack2(a.z, a.w);
            w.z = pack2(b4.x, b4.y);
            w.w = pack2(b4.z, b4.w);
            ((uint4*)h_bf)[gi] = w;
        }
    }
}

// ================ setup_sc: per-(graph,slice) block — recompute scan, scatter CSR
__global__ __launch_bounds__(256) void setup_sc(
    const int* __restrict__ esrc, const int* __restrict__ edst,
    const int* __restrict__ slicecnt, unsigned short* __restrict__ csr,
    int* __restrict__ offs, int* __restrict__ deg)
{
    __shared__ int ssc[256];
    __shared__ int cur[NPG];
    int bid = blockIdx.x;
    int g = bid >> 3, s = bid & 7;
    int gbase = g << 10;
    int tid = threadIdx.x;
    // load all 8 slices' counts for this thread's 4 bins
    int scv[NSLICE][4];
#pragma unroll
    for (int sl = 0; sl < NSLICE; sl++) {
        const int* sc = slicecnt + (((size_t)g * NSLICE + sl) << 10);
#pragma unroll
        for (int i = 0; i < 4; i++) scv[sl][i] = sc[4 * tid + i];
    }
    int d[4], p[4], lsum = 0;
#pragma unroll
    for (int i = 0; i < 4; i++) {
        d[i] = 0;
#pragma unroll
        for (int sl = 0; sl < NSLICE; sl++) d[i] += scv[sl][i];
        p[i] = (d[i] + 1) & ~1;
        lsum += p[i];
    }
    ssc[tid] = lsum;
    __syncthreads();
    for (int off = 1; off < 256; off <<= 1) {
        int v = ssc[tid];
        int vv = (tid >= off) ? ssc[tid - off] : 0;
        __syncthreads();
        ssc[tid] = v + vv;
        __syncthreads();
    }
    int base = ssc[tid] - lsum;
#pragma unroll
    for (int i = 0; i < 4; i++) {
        int node = 4 * tid + i;
        if (s == 0) {
            offs[gbase + node] = base;
            deg[gbase + node] = d[i];
        }
        int c = base;
#pragma unroll
        for (int sl = 0; sl < NSLICE; sl++)
            if (sl < s) c += scv[sl][i];
        cur[node] = c;
        base += p[i];
    }
    __syncthreads();
    const int* ed = edst + (size_t)g * EPG + s * SLICE_E;
    const int* es = esrc + (size_t)g * EPG + s * SLICE_E;
    unsigned short* cg = csr + (size_t)g * CSTRIDE;
#pragma unroll
    for (int it = 0; it < SLICE_E / 256; it++) {
        int e = it * 256 + tid;
        int dd = ed[e] - gbase;
        int sv = es[e] - gbase;
        int pos = atomicAdd(&cur[dd], 1);
        cg[pos] = (unsigned short)sv;
    }
}

// ================ fused_all: aggregate (pull, into LDS) -> GEMM1 -> softmax
//                  -> GEMM2 -> out.  One block per 128 nodes.
__global__ __launch_bounds__(256) void fused_all(
    const short* __restrict__ h_bf, const unsigned short* __restrict__ csr,
    const int* __restrict__ offs, const int* __restrict__ deg_,
    const short* __restrict__ wt, const float* __restrict__ bias,
    const short* __restrict__ feaT, float* __restrict__ out)
{
    __shared__ __align__(16) short ldsN[128 * NSTR];   // neigh tile, reused as P

    int tid = threadIdx.x;
    int tile = blockIdx.x;
    int g = tile >> 3;
    int tile_m = tile * 128;
    int wave = tid >> 6, lane = tid & 63;
    int l31 = lane & 31, hi = lane >> 5;
    int l15 = lane & 15, quad = lane >> 4;

    // ---- phase 0: aggregate this block's 128 nodes into ldsN (bf16, /deg)
    const uint2* rows = (const uint2*)h_bf + ((size_t)g << 10) * 32;  // 32 uint2/row
    const unsigned short* cbase = csr + (size_t)g * CSTRIDE;
    for (int t = 0; t < 32; t++) {
        int node = tile_m + wave * 32 + t;
        int start = offs[node];
        int m = deg_[node];
        const unsigned short* lst = cbase + start;
        float s0 = 0.f, s1 = 0.f, s2 = 0.f, s3 = 0.f;
        int pairs = m >> 1;
        int p = 0;
        for (; p + 4 <= pairs; p += 4) {
            unsigned pp[4];
#pragma unroll
            for (int u = 0; u < 4; u++) pp[u] = *(const unsigned*)(lst + 2 * (p + u));
            uint2 v[4];
#pragma unroll
            for (int u = 0; u < 4; u++) {
                int s = hi ? (int)(pp[u] >> 16) : (int)(pp[u] & 0xffff);
                v[u] = rows[s * 32 + l31];
            }
#pragma unroll
            for (int u = 0; u < 4; u++) {
                s0 += __uint_as_float(v[u].x << 16);
                s1 += __uint_as_float(v[u].x & 0xffff0000u);
                s2 += __uint_as_float(v[u].y << 16);
                s3 += __uint_as_float(v[u].y & 0xffff0000u);
            }
        }
        for (; p < pairs; p++) {
            unsigned pp = *(const unsigned*)(lst + 2 * p);
            int s = hi ? (int)(pp >> 16) : (int)(pp & 0xffff);
            uint2 vv = rows[s * 32 + l31];
            s0 += __uint_as_float(vv.x << 16);
            s1 += __uint_as_float(vv.x & 0xffff0000u);
            s2 += __uint_as_float(vv.y << 16);
            s3 += __uint_as_float(vv.y & 0xffff0000u);
        }
        if (m & 1) {
            int s = lst[m - 1];
            if (!hi) {
                uint2 vv = rows[s * 32 + l31];
                s0 += __uint_as_float(vv.x << 16);
                s1 += __uint_as_float(vv.x & 0xffff0000u);
                s2 += __uint_as_float(vv.y << 16);
                s3 += __uint_as_float(vv.y & 0xffff0000u);
            }
        }
        s0 += __shfl_xor(s0, 32, 64);
        s1 += __shfl_xor(s1, 32, 64);
        s2 += __shfl_xor(s2, 32, 64);
        s3 += __shfl_xor(s3, 32, 64);
        if (!hi) {
            float invd = 1.0f / fmaxf((float)m, 1.0f);
            uint2 w;
            w.x = pack2(s0 * invd, s1 * invd);
            w.y = pack2(s2 * invd, s3 * invd);
            *(uint2*)(ldsN + (wave * 32 + t) * NSTR + l31 * 4) = w;
        }
    }
    __syncthreads();

    // ---- phase 1: GEMM1  logits = [h_bf | neigh] @ wt^T  (K=256)
    floatx4 zz = {0.f, 0.f, 0.f, 0.f};
    floatx4 acc[2][8];
#pragma unroll
    for (int i = 0; i < 2; i++)
#pragma unroll
        for (int j = 0; j < 8; j++) acc[i][j] = zz;

#pragma unroll
    for (int kk = 0; kk < 4; kk++) {
#pragma unroll
        for (int ks = 0; ks < 2; ks++) {
            short8 af[2];
#pragma unroll
            for (int rb = 0; rb < 2; rb++) {
                int m = wave * 32 + rb * 16 + l15;
                if (kk < 2)
                    af[rb] = *reinterpret_cast<const short8*>(
                        h_bf + (size_t)(tile_m + m) * DIN + kk * 64 + ks * 32 + quad * 8);
                else
                    af[rb] = *reinterpret_cast<const short8*>(
                        ldsN + m * NSTR + (kk - 2) * 64 + ks * 32 + quad * 8);
            }
#pragma unroll
            for (int cb = 0; cb < 8; cb++) {
                short8 bf = *reinterpret_cast<const short8*>(
                    wt + (cb * 16 + l15) * 256 + kk * 64 + ks * 32 + quad * 8);
                acc[0][cb] = __builtin_amdgcn_mfma_f32_16x16x32_bf16(af[0], bf, acc[0][cb], 0, 0, 0);
                acc[1][cb] = __builtin_amdgcn_mfma_f32_16x16x32_bf16(af[1], bf, acc[1][cb], 0, 0, 0);
            }
        }
    }

    // ---- phase 2: softmax(relu(+bias)); P -> ldsN (each wave touches only its rows)
    float bv[8];
#pragma unroll
    for (int cb = 0; cb < 8; cb++) bv[cb] = bias[cb * 16 + l15];

#pragma unroll
    for (int rb = 0; rb < 2; rb++) {
#pragma unroll
        for (int v = 0; v < 4; v++) {
            float x[8];
            float m = -1e30f;
#pragma unroll
            for (int cb = 0; cb < 8; cb++) {
                float t = acc[rb][cb][v] + bv[cb];
                t = fmaxf(t, 0.f);
                x[cb] = t;
                m = fmaxf(m, t);
            }
#pragma unroll
            for (int off = 1; off < 16; off <<= 1) m = fmaxf(m, __shfl_xor(m, off, 64));
            float s = 0.f;
#pragma unroll
            for (int cb = 0; cb < 8; cb++) { x[cb] = __expf(x[cb] - m); s += x[cb]; }
#pragma unroll
            for (int off = 1; off < 16; off <<= 1) s += __shfl_xor(s, off, 64);
            float inv = 1.0f / s;
            int row = wave * 32 + rb * 16 + quad * 4 + v;
#pragma unroll
            for (int cb = 0; cb < 8; cb++)
                ldsN[row * NSTR + cb * 16 + l15] = f2bf(x[cb] * inv);
        }
    }
    __syncthreads();

    // ---- phase 3: GEMM2  out = P @ fea[g]  (B direct from global feaT)
    floatx4 oacc[2][8];
#pragma unroll
    for (int i = 0; i < 2; i++)
#pragma unroll
        for (int j = 0; j < 8; j++) oacc[i][j] = zz;

    short8 pf[2][4];
#pragma unroll
    for (int rb = 0; rb < 2; rb++)
#pragma unroll
        for (int ks = 0; ks < 4; ks++)
            pf[rb][ks] = *reinterpret_cast<const short8*>(
                ldsN + (wave * 32 + rb * 16 + l15) * NSTR + ks * 32 + quad * 8);

#pragma unroll
    for (int cb = 0; cb < 8; cb++) {
#pragma unroll
        for (int ks = 0; ks < 4; ks++) {
            short8 bf = *reinterpret_cast<const short8*>(
                feaT + ((size_t)(g * 128) + cb * 16 + l15) * 128 + ks * 32 + quad * 8);
            oacc[0][cb] = __builtin_amdgcn_mfma_f32_16x16x32_bf16(pf[0][ks], bf, oacc[0][cb], 0, 0, 0);
            oacc[1][cb] = __builtin_amdgcn_mfma_f32_16x16x32_bf16(pf[1][ks], bf, oacc[1][cb], 0, 0, 0);
        }
    }

#pragma unroll
    for (int rb = 0; rb < 2; rb++)
#pragma unroll
        for (int v = 0; v < 4; v++) {
            int row = tile_m + wave * 32 + rb * 16 + quad * 4 + v;
#pragma unroll
            for (int cb = 0; cb < 8; cb++)
                out[(size_t)row * 128 + cb * 16 + l15] = oacc[rb][cb][v];
        }
}

extern "C" void kernel_launch(void* const* d_in, const int* in_sizes, int n_in,
                              void* d_out, int out_size, void* d_ws, size_t ws_size,
                              hipStream_t stream) {
    const float* h      = (const float*)d_in[0];
    const float* fea    = (const float*)d_in[1];
    const float* Wself  = (const float*)d_in[2];
    const float* Wneigh = (const float*)d_in[3];
    const float* bias   = (const float*)d_in[4];
    const int*   esrc   = (const int*)d_in[5];
    const int*   edst   = (const int*)d_in[6];
    float* out = (float*)d_out;

    char* ws = (char*)d_ws;
    short* h_bf = (short*)ws;
    size_t off = (size_t)N_NODES * DIN * sizeof(short);                       // 16 MB
    short* wt    = (short*)(ws + off); off += (size_t)128 * 256 * sizeof(short);       // 64 KB
    short* feaT  = (short*)(ws + off); off += (size_t)B_G * 128 * 128 * sizeof(short); // 2 MB
    unsigned short* csr = (unsigned short*)(ws + off); off += (size_t)B_G * CSTRIDE * sizeof(short); // 2.2 MB
    int* offs = (int*)(ws + off); off += (size_t)N_NODES * sizeof(int);       // 256 KB
    int* deg  = (int*)(ws + off); off += (size_t)N_NODES * sizeof(int);       // 256 KB
    int* slicecnt = (int*)(ws + off);                                         // 2 MB

    // setup_a grid: 512 hist blocks + (32768 + 1048576 + 1048576)/256 = 8320 conv blocks
    setup_a<<<B_G * NSLICE + 8320, 256, 0, stream>>>(Wself, Wneigh, fea, h, edst,
                                                     wt, feaT, h_bf, slicecnt);
    setup_sc<<<B_G * NSLICE, 256, 0, stream>>>(esrc, edst, slicecnt, csr, offs, deg);
    fused_all<<<N_NODES / 128, 256, 0, stream>>>(h_bf, csr, offs, deg, wt, bias, feaT, out);
}

// Round 7
// 176.966 us; speedup vs baseline: 1.3257x; 1.3257x over previous
//
#include <hip/hip_runtime.h>

#define N_NODES 65536
#define B_G     64
#define NPG     1024
#define KC      128
#define DIN     128
#define E_EDGES 1048576
#define EPG     16384
#define NSLICE  8
#define SLICE_E (EPG / NSLICE)    // 2048 edges per slice
#define CSTRIDE (EPG + NPG)       // per-graph CSR slots (even-padded offsets)

typedef __attribute__((ext_vector_type(8))) short short8;
typedef __attribute__((ext_vector_type(4))) float floatx4;

static __device__ __forceinline__ short f2bf(float x) {
    unsigned u = __float_as_uint(x);
    unsigned r = (u + 0x7FFF + ((u >> 16) & 1)) >> 16;
    return (short)r;
}
static __device__ __forceinline__ unsigned pack2(float a, float b) {
    return (unsigned)(unsigned short)f2bf(a) | ((unsigned)(unsigned short)f2bf(b) << 16);
}

// ================ setup_a: blocks 0..511 = per-(graph,slice) degree histogram;
//                  blocks 512.. = wt / feaT / h_bf conversions
__global__ __launch_bounds__(256) void setup_a(
    const float* __restrict__ Wself, const float* __restrict__ Wneigh,
    const float* __restrict__ fea, const float* __restrict__ h,
    const int* __restrict__ edst,
    short* __restrict__ wt, short* __restrict__ feaT, short* __restrict__ h_bf,
    int* __restrict__ slicecnt)
{
    int bid = blockIdx.x;
    int tid = threadIdx.x;
    if (bid < B_G * NSLICE) {
        __shared__ int cnt[NPG];
        int g = bid >> 3, s = bid & 7;
        int gbase = g << 10;
        for (int i = tid; i < NPG; i += 256) cnt[i] = 0;
        __syncthreads();
        const int* ed = edst + (size_t)g * EPG + s * SLICE_E;
#pragma unroll
        for (int it = 0; it < SLICE_E / 256; it++)
            atomicAdd(&cnt[ed[it * 256 + tid] - gbase], 1);
        __syncthreads();
        int* sc = slicecnt + ((size_t)bid << 10);
        for (int i = tid; i < NPG; i += 256) sc[i] = cnt[i];
    } else {
        long idx = (long)(bid - B_G * NSLICE) * 256 + tid;
        if (idx < 32768) {
            int n = (int)(idx >> 8), k = (int)(idx & 255);
            float v = (k < 128) ? Wself[k * 128 + n] : Wneigh[(k - 128) * 128 + n];
            wt[idx] = f2bf(v);
        } else if (idx < 32768 + 1048576) {
            long fi = idx - 32768;
            int g = (int)(fi >> 14), d = (int)((fi >> 7) & 127), k = (int)(fi & 127);
            feaT[fi] = f2bf(fea[((long)g * 128 + k) * 128 + d]);
        } else {
            long gi = idx - 32768 - 1048576;   // 8 floats per item
            const float4* hp = (const float4*)h + gi * 2;
            float4 a = hp[0], b4 = hp[1];
            uint4 w;
            w.x = pack2(a.x, a.y);
            w.y = pack2(a.z, a.w);
            w.z = pack2(b4.x, b4.y);
            w.w = pack2(b4.z, b4.w);
            ((uint4*)h_bf)[gi] = w;
        }
    }
}

// ================ setup_sc: per-(graph,slice) block — recompute scan, scatter CSR
__global__ __launch_bounds__(256) void setup_sc(
    const int* __restrict__ esrc, const int* __restrict__ edst,
    const int* __restrict__ slicecnt, unsigned short* __restrict__ csr,
    int* __restrict__ offs, int* __restrict__ deg)
{
    __shared__ int ssc[256];
    __shared__ int cur[NPG];
    int bid = blockIdx.x;
    int g = bid >> 3, s = bid & 7;
    int gbase = g << 10;
    int tid = threadIdx.x;
    int scv[NSLICE][4];
#pragma unroll
    for (int sl = 0; sl < NSLICE; sl++) {
        const int* sc = slicecnt + (((size_t)g * NSLICE + sl) << 10);
#pragma unroll
        for (int i = 0; i < 4; i++) scv[sl][i] = sc[4 * tid + i];
    }
    int d[4], p[4], lsum = 0;
#pragma unroll
    for (int i = 0; i < 4; i++) {
        d[i] = 0;
#pragma unroll
        for (int sl = 0; sl < NSLICE; sl++) d[i] += scv[sl][i];
        p[i] = (d[i] + 1) & ~1;
        lsum += p[i];
    }
    ssc[tid] = lsum;
    __syncthreads();
    for (int off = 1; off < 256; off <<= 1) {
        int v = ssc[tid];
        int vv = (tid >= off) ? ssc[tid - off] : 0;
        __syncthreads();
        ssc[tid] = v + vv;
        __syncthreads();
    }
    int base = ssc[tid] - lsum;
#pragma unroll
    for (int i = 0; i < 4; i++) {
        int node = 4 * tid + i;
        if (s == 0) {
            offs[gbase + node] = base;
            deg[gbase + node] = d[i];
        }
        int c = base;
#pragma unroll
        for (int sl = 0; sl < NSLICE; sl++)
            if (sl < s) c += scv[sl][i];
        cur[node] = c;
        base += p[i];
    }
    __syncthreads();
    const int* ed = edst + (size_t)g * EPG + s * SLICE_E;
    const int* es = esrc + (size_t)g * EPG + s * SLICE_E;
    unsigned short* cg = csr + (size_t)g * CSTRIDE;
#pragma unroll
    for (int it = 0; it < SLICE_E / 256; it++) {
        int e = it * 256 + tid;
        int dd = ed[e] - gbase;
        int sv = es[e] - gbase;
        int pos = atomicAdd(&cur[dd], 1);
        cg[pos] = (unsigned short)sv;
    }
}

// ================ aggregation (pull, bf16): one wave per node,
// 4 edges per gather instruction (16 lanes x uint4 = full 256B row each)
__global__ __launch_bounds__(256) void agg_kernel(
    const short* __restrict__ h_bf, const unsigned short* __restrict__ csr,
    const int* __restrict__ offs, const int* __restrict__ deg_,
    short* __restrict__ neigh)
{
    int g = blockIdx.x & 63;
    int chunk = blockIdx.x >> 6;
    int wave = threadIdx.x >> 6, lane = threadIdx.x & 63;
    int local = chunk * 4 + wave;
    int node = (g << 10) + local;
    int start = offs[node];
    int m = deg_[node];
    const unsigned short* lst = csr + (size_t)g * CSTRIDE + start;
    const uint4* rows = (const uint4*)h_bf + (((size_t)g << 10) * 16);  // 16 uint4/row
    int e4 = lane >> 4;       // edge slot within quad (0..3)
    int l15 = lane & 15;      // uint4 index within row
    float s[8];
#pragma unroll
    for (int i = 0; i < 8; i++) s[i] = 0.f;

    int quads = m >> 2;
    int q = 0;
    for (; q + 4 <= quads; q += 4) {
        int idx[4];
#pragma unroll
        for (int u = 0; u < 4; u++) idx[u] = lst[(q + u) * 4 + e4];
        uint4 v[4];
#pragma unroll
        for (int u = 0; u < 4; u++) v[u] = rows[idx[u] * 16 + l15];
#pragma unroll
        for (int u = 0; u < 4; u++) {
            s[0] += __uint_as_float(v[u].x << 16);
            s[1] += __uint_as_float(v[u].x & 0xffff0000u);
            s[2] += __uint_as_float(v[u].y << 16);
            s[3] += __uint_as_float(v[u].y & 0xffff0000u);
            s[4] += __uint_as_float(v[u].z << 16);
            s[5] += __uint_as_float(v[u].z & 0xffff0000u);
            s[6] += __uint_as_float(v[u].w << 16);
            s[7] += __uint_as_float(v[u].w & 0xffff0000u);
        }
    }
    for (; q < quads; q++) {
        int idx = lst[q * 4 + e4];
        uint4 v = rows[idx * 16 + l15];
        s[0] += __uint_as_float(v.x << 16);
        s[1] += __uint_as_float(v.x & 0xffff0000u);
        s[2] += __uint_as_float(v.y << 16);
        s[3] += __uint_as_float(v.y & 0xffff0000u);
        s[4] += __uint_as_float(v.z << 16);
        s[5] += __uint_as_float(v.z & 0xffff0000u);
        s[6] += __uint_as_float(v.w << 16);
        s[7] += __uint_as_float(v.w & 0xffff0000u);
    }
    int rem = m & 3;
    if (e4 < rem) {
        int idx = lst[(quads << 2) + e4];
        uint4 v = rows[idx * 16 + l15];
        s[0] += __uint_as_float(v.x << 16);
        s[1] += __uint_as_float(v.x & 0xffff0000u);
        s[2] += __uint_as_float(v.y << 16);
        s[3] += __uint_as_float(v.y & 0xffff0000u);
        s[4] += __uint_as_float(v.z << 16);
        s[5] += __uint_as_float(v.z & 0xffff0000u);
        s[6] += __uint_as_float(v.w << 16);
        s[7] += __uint_as_float(v.w & 0xffff0000u);
    }

#pragma unroll
    for (int i = 0; i < 8; i++) {
        s[i] += __shfl_xor(s[i], 16, 64);
        s[i] += __shfl_xor(s[i], 32, 64);
    }
    if (e4 == 0) {
        float invd = 1.0f / fmaxf((float)m, 1.0f);
        uint4 w;
        w.x = pack2(s[0] * invd, s[1] * invd);
        w.y = pack2(s[2] * invd, s[3] * invd);
        w.z = pack2(s[4] * invd, s[5] * invd);
        w.w = pack2(s[6] * invd, s[7] * invd);
        ((uint4*)neigh)[(size_t)node * 16 + l15] = w;
    }
}

// ================ fused: assign = softmax(relu([h_bf|neigh] @ wt^T + b));
//                  out = assign @ fea.  Direct global A/B loads; LDS only for P.
__global__ __launch_bounds__(256) void fused_kernel(
    const short* __restrict__ h_bf, const short* __restrict__ neigh,
    const short* __restrict__ wt, const float* __restrict__ bias,
    const short* __restrict__ feaT, float* __restrict__ out)
{
    __shared__ __align__(16) short ldsP[128 * 132];

    int tid = threadIdx.x;
    int g = blockIdx.x & 63;         // XCD swizzle: graph g stays on XCD g%8
    int ts = blockIdx.x >> 6;
    int tile_m = (g << 10) + ts * 128;
    int wave = tid >> 6, lane = tid & 63;
    int l15 = lane & 15, quad = lane >> 4;

    floatx4 zz = {0.f, 0.f, 0.f, 0.f};
    floatx4 acc[2][8];
#pragma unroll
    for (int i = 0; i < 2; i++)
#pragma unroll
        for (int j = 0; j < 8; j++) acc[i][j] = zz;

    // ---- GEMM1: logits = [h_bf | neigh] @ wt^T  (K=256), all operands direct
#pragma unroll
    for (int kk = 0; kk < 4; kk++) {
#pragma unroll
        for (int ks = 0; ks < 2; ks++) {
            short8 af[2];
#pragma unroll
            for (int rb = 0; rb < 2; rb++) {
                int m = wave * 32 + rb * 16 + l15;
                const short* base = (kk < 2) ? h_bf + (size_t)(tile_m + m) * DIN + kk * 64
                                             : neigh + (size_t)(tile_m + m) * DIN + (kk - 2) * 64;
                af[rb] = *reinterpret_cast<const short8*>(base + ks * 32 + quad * 8);
            }
#pragma unroll
            for (int cb = 0; cb < 8; cb++) {
                short8 bf = *reinterpret_cast<const short8*>(
                    wt + (cb * 16 + l15) * 256 + kk * 64 + ks * 32 + quad * 8);
                acc[0][cb] = __builtin_amdgcn_mfma_f32_16x16x32_bf16(af[0], bf, acc[0][cb], 0, 0, 0);
                acc[1][cb] = __builtin_amdgcn_mfma_f32_16x16x32_bf16(af[1], bf, acc[1][cb], 0, 0, 0);
            }
        }
    }

    // ---- softmax(relu(+bias)); P -> ldsP (stride 132, conflict-free)
    float bv[8];
#pragma unroll
    for (int cb = 0; cb < 8; cb++) bv[cb] = bias[cb * 16 + l15];

#pragma unroll
    for (int rb = 0; rb < 2; rb++) {
#pragma unroll
        for (int v = 0; v < 4; v++) {
            float x[8];
            float m = -1e30f;
#pragma unroll
            for (int cb = 0; cb < 8; cb++) {
                float t = acc[rb][cb][v] + bv[cb];
                t = fmaxf(t, 0.f);
                x[cb] = t;
                m = fmaxf(m, t);
            }
#pragma unroll
            for (int off = 1; off < 16; off <<= 1) m = fmaxf(m, __shfl_xor(m, off, 64));
            float sum = 0.f;
#pragma unroll
            for (int cb = 0; cb < 8; cb++) { x[cb] = __expf(x[cb] - m); sum += x[cb]; }
#pragma unroll
            for (int off = 1; off < 16; off <<= 1) sum += __shfl_xor(sum, off, 64);
            float inv = 1.0f / sum;
            int row = wave * 32 + rb * 16 + quad * 4 + v;
#pragma unroll
            for (int cb = 0; cb < 8; cb++)
                ldsP[row * 132 + cb * 16 + l15] = f2bf(x[cb] * inv);
        }
    }
    __syncthreads();

    // ---- GEMM2: out = P @ fea[g]  (B direct from global feaT)
    floatx4 oacc[2][8];
#pragma unroll
    for (int i = 0; i < 2; i++)
#pragma unroll
        for (int j = 0; j < 8; j++) oacc[i][j] = zz;

    short8 pf[2][4];
#pragma unroll
    for (int rb = 0; rb < 2; rb++)
#pragma unroll
        for (int ks = 0; ks < 4; ks++)
            pf[rb][ks] = *reinterpret_cast<const short8*>(
                ldsP + (wave * 32 + rb * 16 + l15) * 132 + ks * 32 + quad * 8);

#pragma unroll
    for (int cb = 0; cb < 8; cb++) {
#pragma unroll
        for (int ks = 0; ks < 4; ks++) {
            short8 bf = *reinterpret_cast<const short8*>(
                feaT + ((size_t)(g * 128) + cb * 16 + l15) * 128 + ks * 32 + quad * 8);
            oacc[0][cb] = __builtin_amdgcn_mfma_f32_16x16x32_bf16(pf[0][ks], bf, oacc[0][cb], 0, 0, 0);
            oacc[1][cb] = __builtin_amdgcn_mfma_f32_16x16x32_bf16(pf[1][ks], bf, oacc[1][cb], 0, 0, 0);
        }
    }

#pragma unroll
    for (int rb = 0; rb < 2; rb++)
#pragma unroll
        for (int v = 0; v < 4; v++) {
            int row = tile_m + wave * 32 + rb * 16 + quad * 4 + v;
#pragma unroll
            for (int cb = 0; cb < 8; cb++)
                out[(size_t)row * 128 + cb * 16 + l15] = oacc[rb][cb][v];
        }
}

extern "C" void kernel_launch(void* const* d_in, const int* in_sizes, int n_in,
                              void* d_out, int out_size, void* d_ws, size_t ws_size,
                              hipStream_t stream) {
    const float* h      = (const float*)d_in[0];
    const float* fea    = (const float*)d_in[1];
    const float* Wself  = (const float*)d_in[2];
    const float* Wneigh = (const float*)d_in[3];
    const float* bias   = (const float*)d_in[4];
    const int*   esrc   = (const int*)d_in[5];
    const int*   edst   = (const int*)d_in[6];
    float* out = (float*)d_out;

    char* ws = (char*)d_ws;
    short* h_bf = (short*)ws;
    size_t off = (size_t)N_NODES * DIN * sizeof(short);                       // 16 MB
    short* neigh = (short*)(ws + off); off += (size_t)N_NODES * DIN * sizeof(short);   // 16 MB
    short* wt    = (short*)(ws + off); off += (size_t)128 * 256 * sizeof(short);       // 64 KB
    short* feaT  = (short*)(ws + off); off += (size_t)B_G * 128 * 128 * sizeof(short); // 2 MB
    unsigned short* csr = (unsigned short*)(ws + off); off += (size_t)B_G * CSTRIDE * sizeof(short); // 2.2 MB
    int* offs = (int*)(ws + off); off += (size_t)N_NODES * sizeof(int);       // 256 KB
    int* deg  = (int*)(ws + off); off += (size_t)N_NODES * sizeof(int);       // 256 KB
    int* slicecnt = (int*)(ws + off);                                         // 2 MB

    setup_a<<<B_G * NSLICE + 8320, 256, 0, stream>>>(Wself, Wneigh, fea, h, edst,
                                                     wt, feaT, h_bf, slicecnt);
    setup_sc<<<B_G * NSLICE, 256, 0, stream>>>(esrc, edst, slicecnt, csr, offs, deg);
    agg_kernel<<<256 * B_G, 256, 0, stream>>>(h_bf, csr, offs, deg, neigh);
    fused_kernel<<<N_NODES / 128, 256, 0, stream>>>(h_bf, neigh, wt, bias, feaT, out);
}